// Round 6
// baseline (1376.745 us; speedup 1.0000x reference)
//
#include <hip/hip_runtime.h>
#include <math.h>

// ---------------------------------------------------------------------------
// STaRNet forward, fully fused fp32 pipeline.
//
//  k_prep : fold spatial convs+BN+wf-conv+BN into M(50x22)+biasf(50);
//           fold temporal BN into conv taps wtf[450][64] + bias bt[450].
//  k_main : per (batch, 256-t tile): xf tile in LDS, per-thread t:
//           h[450] on the fly -> y[64] = W^T h; sum(h^2) partials.
//           Weight loads laundered through readfirstlane -> scalar pipe.
//  k_eig  : per batch, 1024 threads: syrk y y^T (transposed LDS staging,
//           b128 reads, 4x4 on 256 thr); parallel cyclic Jacobi, 16 waves
//           x 2 pairs, conflict-free odd-pitch A/V, inline params,
//           LAPACK-style rotation skip, 2 barriers/round, 6 sweeps;
//           log-eig recon; triu -> FC -> out.
// ---------------------------------------------------------------------------

typedef __attribute__((ext_vector_type(2))) float v2f;
typedef __attribute__((ext_vector_type(4))) float v4f;

#define NSWEEP 6
#define JTOL   1e-7f

// ws float offsets
#define WS_M      0         // 50*22
#define WS_BIASF  1100      // 50
#define WS_WTF    1152      // 450*64
#define WS_BT     29952     // 450
#define WS_HPART  30402     // 512
#define WS_Y      32768     // 128*64*1001

// launder a wave-uniform pointer into SGPRs so the compiler emits s_loads
__device__ __forceinline__ const float* uniptr(const float* p) {
    uint64_t v = (uint64_t)p;
    uint32_t lo = __builtin_amdgcn_readfirstlane((uint32_t)v);
    uint32_t hi = __builtin_amdgcn_readfirstlane((uint32_t)(v >> 32));
    return (const float*)(((uint64_t)hi << 32) | (uint64_t)lo);
}

__global__ void k_prep(
    const float* __restrict__ ws0, const float* __restrict__ ws1, const float* __restrict__ ws2,
    const float* __restrict__ bsg, const float* __restrict__ bsb, const float* __restrict__ bsm, const float* __restrict__ bsv,
    const float* __restrict__ wf,
    const float* __restrict__ bfg, const float* __restrict__ bfb, const float* __restrict__ bfm, const float* __restrict__ bfv,
    const float* __restrict__ wt0, const float* __restrict__ wt1, const float* __restrict__ wt2,
    const float* __restrict__ btg, const float* __restrict__ btb, const float* __restrict__ btm, const float* __restrict__ btv,
    float* __restrict__ wsf)
{
    int tid = threadIdx.x;
    if (tid < 450) {
        int c = tid;
        int i = c / 150, o = c % 150;
        int k = (i == 0) ? 64 : ((i == 1) ? 32 : 16);
        float g = btg[i*150 + o], b = btb[i*150 + o];
        float m = btm[i*150 + o], v = btv[i*150 + o];
        float s = g * rsqrtf(v + 1e-5f);
        wsf[WS_BT + c] = b - s * m;
        float* wrow = wsf + WS_WTF + c * 64;
        for (int t = 0; t < 64; ++t) wrow[t] = 0.f;
        const float* w = (i == 0) ? wt0 : ((i == 1) ? wt1 : wt2);
        int off = 32 - k / 2;
        for (int t = 0; t < k; ++t) wrow[off + t] = s * w[o*k + t];
    }
    if (tid < 50) {
        int f = tid;
        float sf = bfg[f] * rsqrtf(bfv[f] + 1e-5f);
        float row[22];
        for (int c = 0; c < 22; ++c) row[c] = 0.f;
        float bacc = 0.f;
        for (int j = 0; j < 60; ++j) {
            int i, k, j0; const float* wsp;
            if (j < 22)      { i = 0; k = 1; j0 = j;      wsp = ws0; }
            else if (j < 42) { i = 1; k = 3; j0 = j - 22; wsp = ws1; }
            else             { i = 2; k = 5; j0 = j - 42; wsp = ws2; }
            float si = bsg[i] * rsqrtf(bsv[i] + 1e-5f);
            float bi = bsb[i] - si * bsm[i];
            float wfj = wf[f*60 + j];
            for (int d = 0; d < k; ++d) row[j0 + d] += wfj * si * wsp[d];
            bacc += wfj * bi;
        }
        for (int c = 0; c < 22; ++c) wsf[WS_M + f*22 + c] = sf * row[c];
        wsf[WS_BIASF + f] = sf * (bacc - bfm[f]) + bfb[f];
    }
}

// ---------------------------------------------------------------------------
__global__ __launch_bounds__(256) void k_main(
    const float* __restrict__ x, const float* __restrict__ wsf,
    const float* __restrict__ Wmap, float* __restrict__ y,
    float* __restrict__ hpart)
{
    const int b    = blockIdx.x >> 2;
    const int tile = blockIdx.x & 3;
    const int t0   = tile * 256;
    const int tid  = threadIdx.x;

    __shared__ float xt[50][320];   // xf tile, zero-padded (62.5 KB)
    __shared__ float wred[4];

    const float* Mg    = uniptr(wsf + WS_M);
    const float* biasf = uniptr(wsf + WS_BIASF);
    const float* wtf   = uniptr(wsf + WS_WTF);
    const float* bt    = uniptr(wsf + WS_BT);

    for (int col = tid; col < 320; col += 256) {
        int tx = t0 + col - 32;
        if (tx >= 0 && tx < 1000) {
            float xv[22];
            #pragma unroll
            for (int c = 0; c < 22; ++c) xv[c] = x[(b*22 + c)*1000 + tx];
            for (int g = 0; g < 50; ++g) {
                float a = biasf[g];
                #pragma unroll
                for (int c = 0; c < 22; ++c) a += Mg[g*22 + c] * xv[c];
                xt[g][col] = a;
            }
        } else {
            for (int g = 0; g < 50; ++g) xt[g][col] = 0.f;
        }
    }
    __syncthreads();

    const int t = t0 + tid;
    const bool act = (t <= 1000);
    v2f yv2[32];
    #pragma unroll
    for (int m = 0; m < 32; ++m) yv2[m] = (v2f){0.f, 0.f};
    float hsq = 0.f;

    if (act) {
        for (int g = 0; g < 50; ++g) {
            const float* xb = &xt[g][tid];
            const float* w0 = uniptr(wtf + (3*g) * 64);
            const float* w1 = uniptr(wtf + (150 + 3*g) * 64);
            const float* w2 = uniptr(wtf + (300 + 3*g) * 64);
            v2f h2[9];
            #pragma unroll
            for (int j = 0; j < 9; ++j) h2[j] = (v2f){0.f, 0.f};
            #pragma unroll
            for (int tau = 0; tau < 64; tau += 2) {
                v2f xv = (v2f){xb[tau], xb[tau + 1]};
                h2[0] += (*(const v2f*)(w0 + tau))       * xv;
                h2[1] += (*(const v2f*)(w0 + 64 + tau))  * xv;
                h2[2] += (*(const v2f*)(w0 + 128 + tau)) * xv;
                if (tau >= 16 && tau < 48) {
                    h2[3] += (*(const v2f*)(w1 + tau))       * xv;
                    h2[4] += (*(const v2f*)(w1 + 64 + tau))  * xv;
                    h2[5] += (*(const v2f*)(w1 + 128 + tau)) * xv;
                }
                if (tau >= 24 && tau < 40) {
                    h2[6] += (*(const v2f*)(w2 + tau))       * xv;
                    h2[7] += (*(const v2f*)(w2 + 64 + tau))  * xv;
                    h2[8] += (*(const v2f*)(w2 + 128 + tau)) * xv;
                }
            }
            #pragma unroll
            for (int j = 0; j < 9; ++j) {
                int c = (j < 3) ? (3*g + j)
                      : (j < 6) ? (150 + 3*g + (j - 3))
                                : (300 + 3*g + (j - 6));
                float hv = h2[j].x + h2[j].y + bt[c];
                hsq += hv * hv;
                const v2f* wr2 = (const v2f*)uniptr(Wmap + c * 64);
                v2f hv2 = (v2f){hv, hv};
                #pragma unroll
                for (int m = 0; m < 32; ++m) yv2[m] += wr2[m] * hv2;
            }
        }
        #pragma unroll
        for (int k = 0; k < 32; ++k) {
            y[(b*64 + 2*k)*1001 + t]     = yv2[k].x;
            y[(b*64 + 2*k + 1)*1001 + t] = yv2[k].y;
        }
    }

    for (int off = 32; off > 0; off >>= 1) hsq += __shfl_down(hsq, off, 64);
    int wid = tid >> 6, lane = tid & 63;
    if (lane == 0) wred[wid] = hsq;
    __syncthreads();
    if (tid == 0) hpart[blockIdx.x] = wred[0] + wred[1] + wred[2] + wred[3];
}

// ---------------------------------------------------------------------------
// pair schedule: round rr, pair j: j==0 -> (63, rr); else
// p=(rr+j)%63, q=(rr+63-j)%63. All pairs disjoint within a round.
__device__ __forceinline__ void pair_pq(int rr, int j, int& p, int& q) {
    if (j == 0) { p = 63; q = rr; }
    else {
        int a = rr + j;       if (a >= 63) a -= 63;
        int c = rr + 63 - j;  if (c >= 63) c -= 63;
        p = a; q = c;
    }
}

union SMu {
    float ytT[128][68];                              // syrk staging, transposed (34816 B)
    struct { float A[64][65]; float V[64][65]; } j;  // Jacobi (33280 B)
};

__global__ __launch_bounds__(1024) void k_eig(
    const float* __restrict__ y, const float* __restrict__ hpart,
    const float* __restrict__ fcw, const float* __restrict__ fcb,
    float* __restrict__ out)
{
    const int b    = blockIdx.x;
    const int tid  = threadIdx.x;
    const int w    = tid >> 6;     // wave 0..15
    const int lane = tid & 63;

    __shared__ SMu U;
    __shared__ float le[64];
    __shared__ float wred2[16];

    // ---- syrk: acc = y y^T; transposed staging so the MAC phase reads
    //      2x ds_read_b128 per tt (16B-aligned: pitch 68).  MAC on first
    //      256 threads (4x4 blocking), staging by all 16 waves. ----
    const int mg = tid >> 4, ng = tid & 15;       // valid for tid<256
    const int m0 = mg * 4,  n0 = ng * 4;
    float acc[16];
    #pragma unroll
    for (int i = 0; i < 16; ++i) acc[i] = 0.f;
    for (int tile = 0; tile < 8; ++tile) {
        #pragma unroll
        for (int k = 0; k < 8; ++k) {
            int idx = tid + k*1024;
            int col = idx >> 7, row = idx & 127;   // col=m, row=t-in-tile
            int tg = tile * 128 + row;
            U.ytT[row][col] = (tg <= 1000) ? y[(b*64 + col)*1001 + tg] : 0.f;
        }
        __syncthreads();
        if (tid < 256) {
            for (int tt = 0; tt < 128; ++tt) {
                v4f ym = *(const v4f*)&U.ytT[tt][m0];
                v4f yn = *(const v4f*)&U.ytT[tt][n0];
                #pragma unroll
                for (int i = 0; i < 4; ++i)
                    #pragma unroll
                    for (int j = 0; j < 4; ++j) acc[i*4 + j] += ym[i] * yn[j];
            }
        }
        __syncthreads();
    }
    if (tid < 256) {
        float hs = hpart[b*4] + hpart[b*4+1] + hpart[b*4+2] + hpart[b*4+3];
        float mu = hs / (999.f * 450.f);
        #pragma unroll
        for (int i = 0; i < 4; ++i)
            #pragma unroll
            for (int j = 0; j < 4; ++j) {
                int mm = m0 + i, nn = n0 + j;
                U.j.A[mm][nn] = acc[i*4 + j] * (0.95f / 999.f)
                              + ((mm == nn) ? 0.05f * mu : 0.f);
                U.j.V[mm][nn] = (mm == nn) ? 1.f : 0.f;
            }
    }
    __syncthreads();

    // ---- parallel cyclic Jacobi: 16 waves x 2 pairs, conflict-free b32,
    //      LAPACK-style rotation skip (wave-uniform branches) ----
    for (int sweep = 0; sweep < NSWEEP; ++sweep)
    for (int rr = 0; rr < 63; ++rr) {
        float cp, sp; bool tv;
        {
            int jj = w + ((lane & 1) << 4);
            int p, q; pair_pq(rr, jj, p, q);
            float app = U.j.A[p][p], aqq = U.j.A[q][q], apq = U.j.A[p][q];
            tv = (fabsf(apq) <= JTOL * sqrtf(fabsf(app * aqq)));
            float apqs = tv ? 1.f : apq;
            float tau = (aqq - app) * __builtin_amdgcn_rcpf(2.f * apqs);
            float tt = copysignf(1.f, tau) / (fabsf(tau) + sqrtf(1.f + tau*tau));
            float c = rsqrtf(1.f + tt*tt);
            float s = tt * c;
            cp = tv ? 1.f : c;
            sp = tv ? 0.f : s;
        }
        unsigned long long bal = __ballot(tv);
        const bool t0 = (bal & 1ull) != 0ull;
        const bool t1 = (bal & 2ull) != 0ull;
        float c0 = __shfl(cp, 0, 64), s0 = __shfl(sp, 0, 64);
        float c1 = __shfl(cp, 1, 64), s1 = __shfl(sp, 1, 64);
        int p0, q0, p1, q1;
        pair_pq(rr, w,      p0, q0);
        pair_pq(rr, w + 16, p1, q1);

        // col phase (A and V), per-pair wave-uniform skip
        if (!t0) {
            float a0p = U.j.A[lane][p0], a0q = U.j.A[lane][q0];
            float v0p = U.j.V[lane][p0], v0q = U.j.V[lane][q0];
            U.j.A[lane][p0] = c0*a0p - s0*a0q;
            U.j.A[lane][q0] = s0*a0p + c0*a0q;
            U.j.V[lane][p0] = c0*v0p - s0*v0q;
            U.j.V[lane][q0] = s0*v0p + c0*v0q;
        }
        if (!t1) {
            float a1p = U.j.A[lane][p1], a1q = U.j.A[lane][q1];
            float v1p = U.j.V[lane][p1], v1q = U.j.V[lane][q1];
            U.j.A[lane][p1] = c1*a1p - s1*a1q;
            U.j.A[lane][q1] = s1*a1p + c1*a1q;
            U.j.V[lane][p1] = c1*v1p - s1*v1q;
            U.j.V[lane][q1] = s1*v1p + c1*v1q;
        }
        __syncthreads();

        // row phase (A only)
        if (!t0) {
            float r0p = U.j.A[p0][lane], r0q = U.j.A[q0][lane];
            U.j.A[p0][lane] = c0*r0p - s0*r0q;
            U.j.A[q0][lane] = s0*r0p + c0*r0q;
        }
        if (!t1) {
            float r1p = U.j.A[p1][lane], r1q = U.j.A[q1][lane];
            U.j.A[p1][lane] = c1*r1p - s1*r1q;
            U.j.A[q1][lane] = s1*r1p + c1*r1q;
        }
        __syncthreads();
    }

    // ---- log-eig reconstruction + FC (first 256 threads) ----
    if (tid < 64) le[tid] = logf(fmaxf(U.j.A[tid][tid], 1e-6f));
    __syncthreads();

    if (tid < 256) {
        float lm[16];
        #pragma unroll
        for (int i = 0; i < 16; ++i) lm[i] = 0.f;
        for (int k = 0; k < 64; ++k) {
            float l = le[k];
            float vm[4], vn[4];
            #pragma unroll
            for (int i = 0; i < 4; ++i) vm[i] = U.j.V[m0 + i][k] * l;
            #pragma unroll
            for (int j = 0; j < 4; ++j) vn[j] = U.j.V[n0 + j][k];
            #pragma unroll
            for (int i = 0; i < 4; ++i)
                #pragma unroll
                for (int j = 0; j < 4; ++j) lm[i*4 + j] += vm[i] * vn[j];
        }

        float fa[4];
        #pragma unroll
        for (int o = 0; o < 4; ++o) fa[o] = 0.f;
        #pragma unroll
        for (int i = 0; i < 4; ++i)
            #pragma unroll
            for (int j = 0; j < 4; ++j) {
                int gi = m0 + i, gj = n0 + j;
                if (gi <= gj) {
                    int p = gi*64 - (gi*(gi-1))/2 + (gj - gi);
                    float lv = lm[i*4 + j];
                    #pragma unroll
                    for (int o = 0; o < 4; ++o) fa[o] += lv * fcw[o*2080 + p];
                }
            }

        #pragma unroll
        for (int o = 0; o < 4; ++o)
            for (int off = 32; off > 0; off >>= 1)
                fa[o] += __shfl_down(fa[o], off, 64);
        if (lane == 0) {
            #pragma unroll
            for (int o = 0; o < 4; ++o) wred2[w*4 + o] = fa[o];
        }
    }
    __syncthreads();
    if (tid < 4)
        out[b*4 + tid] = wred2[tid] + wred2[4 + tid] + wred2[8 + tid]
                       + wred2[12 + tid] + fcb[tid];
}

// ---------------------------------------------------------------------------
extern "C" void kernel_launch(void* const* d_in, const int* in_sizes, int n_in,
                              void* d_out, int out_size, void* d_ws, size_t ws_size,
                              hipStream_t stream) {
    (void)in_sizes; (void)n_in; (void)out_size; (void)ws_size;
    const float* x   = (const float*)d_in[0];
    const float* ws0 = (const float*)d_in[1];
    const float* ws1 = (const float*)d_in[2];
    const float* ws2 = (const float*)d_in[3];
    const float* bsg = (const float*)d_in[4];
    const float* bsb = (const float*)d_in[5];
    const float* bsm = (const float*)d_in[6];
    const float* bsv = (const float*)d_in[7];
    const float* wf  = (const float*)d_in[8];
    const float* bfg = (const float*)d_in[9];
    const float* bfb = (const float*)d_in[10];
    const float* bfm = (const float*)d_in[11];
    const float* bfv = (const float*)d_in[12];
    const float* wt0 = (const float*)d_in[13];
    const float* wt1 = (const float*)d_in[14];
    const float* wt2 = (const float*)d_in[15];
    const float* btg = (const float*)d_in[16];
    const float* btb = (const float*)d_in[17];
    const float* btm = (const float*)d_in[18];
    const float* btv = (const float*)d_in[19];
    const float* Wm  = (const float*)d_in[20];
    const float* fcw = (const float*)d_in[21];
    const float* fcb = (const float*)d_in[22];

    float* wsf   = (float*)d_ws;
    float* yb    = wsf + WS_Y;
    float* hpart = wsf + WS_HPART;

    k_prep<<<1, 512, 0, stream>>>(ws0, ws1, ws2, bsg, bsb, bsm, bsv,
                                  wf, bfg, bfb, bfm, bfv,
                                  wt0, wt1, wt2, btg, btb, btm, btv, wsf);
    k_main<<<512, 256, 0, stream>>>(x, wsf, Wm, yb, hpart);
    k_eig<<<128, 1024, 0, stream>>>(yb, hpart, fcw, fcb, (float*)d_out);
}

// Round 7
// 796.601 us; speedup vs baseline: 1.7283x; 1.7283x over previous
//
#include <hip/hip_runtime.h>
#include <math.h>

// ---------------------------------------------------------------------------
// STaRNet forward, fully fused fp32 pipeline.
//
//  k_prep : fold spatial convs+BN+wf-conv+BN into M(50x22)+biasf(50);
//           fold temporal BN into COMPACT conv taps wtf[50][336] + bt[450].
//  k_main : per (batch, 256-t tile): xf tile in LDS, per-thread t:
//           h[450] on the fly -> y[64] = W^T h (v4f weight loads);
//           sum(h^2) partials.
//  k_eig  : per batch, 1024 threads: syrk y y^T (transposed staging, b128);
//           ONE-SIDED Jacobi on G=A (SPD): 32 pairs/round = 16 waves x 2
//           32-lane groups, b64 column ops, tracked norms, 1 barrier/round,
//           sweep early-exit; lambda=||g||, v=g/lambda -> log recon -> FC.
// ---------------------------------------------------------------------------

typedef __attribute__((ext_vector_type(4))) float v4f;

#define MAXSWEEP 12
#define JTOL     1e-6f

// ws float offsets
#define WS_M      0         // 50*22
#define WS_BIASF  1100      // 50
#define WS_WTF    1152      // 50*336 compact taps
#define WS_BT     17952     // 450
#define WS_HPART  18432     // 512
#define WS_Y      32768     // 128*64*1001

__global__ void k_prep(
    const float* __restrict__ ws0, const float* __restrict__ ws1, const float* __restrict__ ws2,
    const float* __restrict__ bsg, const float* __restrict__ bsb, const float* __restrict__ bsm, const float* __restrict__ bsv,
    const float* __restrict__ wf,
    const float* __restrict__ bfg, const float* __restrict__ bfb, const float* __restrict__ bfm, const float* __restrict__ bfv,
    const float* __restrict__ wt0, const float* __restrict__ wt1, const float* __restrict__ wt2,
    const float* __restrict__ btg, const float* __restrict__ btb, const float* __restrict__ btm, const float* __restrict__ btv,
    float* __restrict__ wsf)
{
    int tid = threadIdx.x;
    if (tid < 450) {
        int c = tid;
        int i = c / 150, o = c % 150;
        int g = o / 3,   jr = o % 3;
        int k = (i == 0) ? 64 : ((i == 1) ? 32 : 16);
        float ga = btg[i*150 + o], bb = btb[i*150 + o];
        float mm = btm[i*150 + o], vv = btv[i*150 + o];
        float s = ga * rsqrtf(vv + 1e-5f);
        wsf[WS_BT + c] = bb - s * mm;
        int base = g*336 + ((i == 0) ? jr*64 : (i == 1) ? 192 + jr*32 : 288 + jr*16);
        const float* wsrc = (i == 0) ? wt0 : ((i == 1) ? wt1 : wt2);
        float* dst = wsf + WS_WTF + base;
        for (int t = 0; t < k; ++t) dst[t] = s * wsrc[o*k + t];
    }
    if (tid < 50) {
        int f = tid;
        float sf = bfg[f] * rsqrtf(bfv[f] + 1e-5f);
        float row[22];
        for (int c = 0; c < 22; ++c) row[c] = 0.f;
        float bacc = 0.f;
        for (int j = 0; j < 60; ++j) {
            int i, k, j0; const float* wsp;
            if (j < 22)      { i = 0; k = 1; j0 = j;      wsp = ws0; }
            else if (j < 42) { i = 1; k = 3; j0 = j - 22; wsp = ws1; }
            else             { i = 2; k = 5; j0 = j - 42; wsp = ws2; }
            float si = bsg[i] * rsqrtf(bsv[i] + 1e-5f);
            float bi = bsb[i] - si * bsm[i];
            float wfj = wf[f*60 + j];
            for (int d = 0; d < k; ++d) row[j0 + d] += wfj * si * wsp[d];
            bacc += wfj * bi;
        }
        for (int c = 0; c < 22; ++c) wsf[WS_M + f*22 + c] = sf * row[c];
        wsf[WS_BIASF + f] = sf * (bacc - bfm[f]) + bfb[f];
    }
}

// ---------------------------------------------------------------------------
__global__ __launch_bounds__(256) void k_main(
    const float* __restrict__ x, const float* __restrict__ wsf,
    const float* __restrict__ Wmap, float* __restrict__ y,
    float* __restrict__ hpart)
{
    const int b    = blockIdx.x >> 2;
    const int tile = blockIdx.x & 3;
    const int t0   = tile * 256;
    const int tid  = threadIdx.x;

    __shared__ float xt[50][320];   // xf tile, zero-padded (62.5 KB)
    __shared__ float wred[4];

    const float* Mg    = wsf + WS_M;
    const float* biasf = wsf + WS_BIASF;
    const float* wtf   = wsf + WS_WTF;
    const float* bt    = wsf + WS_BT;

    for (int col = tid; col < 320; col += 256) {
        int tx = t0 + col - 32;
        if (tx >= 0 && tx < 1000) {
            float xv[22];
            #pragma unroll
            for (int c = 0; c < 22; ++c) xv[c] = x[(b*22 + c)*1000 + tx];
            for (int g = 0; g < 50; ++g) {
                float a = biasf[g];
                #pragma unroll
                for (int c = 0; c < 22; ++c) a += Mg[g*22 + c] * xv[c];
                xt[g][col] = a;
            }
        } else {
            for (int g = 0; g < 50; ++g) xt[g][col] = 0.f;
        }
    }
    __syncthreads();

    const int t = t0 + tid;
    const bool act = (t <= 1000);
    v4f yv4[16];
    #pragma unroll
    for (int m = 0; m < 16; ++m) yv4[m] = (v4f){0.f, 0.f, 0.f, 0.f};
    float hsq = 0.f;

    if (act) {
        for (int g = 0; g < 50; ++g) {
            const float* xb = &xt[g][tid];
            const float* wg = wtf + g * 336;   // compact: [0..191]=b0, [192..287]=b1, [288..335]=b2
            v4f h4[9];
            #pragma unroll
            for (int j = 0; j < 9; ++j) h4[j] = (v4f){0.f, 0.f, 0.f, 0.f};
            #pragma unroll
            for (int tau = 0; tau < 64; tau += 4) {
                v4f xv = (v4f){xb[tau], xb[tau+1], xb[tau+2], xb[tau+3]};
                h4[0] += (*(const v4f*)(wg + tau))       * xv;
                h4[1] += (*(const v4f*)(wg + 64 + tau))  * xv;
                h4[2] += (*(const v4f*)(wg + 128 + tau)) * xv;
                if (tau >= 16 && tau < 48) {
                    int u = tau - 16;
                    h4[3] += (*(const v4f*)(wg + 192 + u)) * xv;
                    h4[4] += (*(const v4f*)(wg + 224 + u)) * xv;
                    h4[5] += (*(const v4f*)(wg + 256 + u)) * xv;
                }
                if (tau >= 24 && tau < 40) {
                    int u = tau - 24;
                    h4[6] += (*(const v4f*)(wg + 288 + u)) * xv;
                    h4[7] += (*(const v4f*)(wg + 304 + u)) * xv;
                    h4[8] += (*(const v4f*)(wg + 320 + u)) * xv;
                }
            }
            #pragma unroll
            for (int j = 0; j < 9; ++j) {
                int c = (j < 3) ? (3*g + j)
                      : (j < 6) ? (150 + 3*g + (j - 3))
                                : (300 + 3*g + (j - 6));
                float hv = (h4[j].x + h4[j].y) + (h4[j].z + h4[j].w) + bt[c];
                hsq += hv * hv;
                const v4f* wr4 = (const v4f*)(Wmap + c * 64);  // wave-uniform
                v4f hv4 = (v4f){hv, hv, hv, hv};
                #pragma unroll
                for (int m = 0; m < 16; ++m) yv4[m] += wr4[m] * hv4;
            }
        }
        #pragma unroll
        for (int k = 0; k < 16; ++k) {
            y[(b*64 + 4*k)*1001 + t]     = yv4[k].x;
            y[(b*64 + 4*k + 1)*1001 + t] = yv4[k].y;
            y[(b*64 + 4*k + 2)*1001 + t] = yv4[k].z;
            y[(b*64 + 4*k + 3)*1001 + t] = yv4[k].w;
        }
    }

    for (int off = 32; off > 0; off >>= 1) hsq += __shfl_down(hsq, off, 64);
    int wid = tid >> 6, lane = tid & 63;
    if (lane == 0) wred[wid] = hsq;
    __syncthreads();
    if (tid == 0) hpart[blockIdx.x] = wred[0] + wred[1] + wred[2] + wred[3];
}

// ---------------------------------------------------------------------------
// pair schedule: round rr, pair j: j==0 -> (63, rr); else
// p=(rr+j)%63, q=(rr+63-j)%63. All pairs disjoint within a round.
__device__ __forceinline__ void pair_pq(int rr, int j, int& p, int& q) {
    if (j == 0) { p = 63; q = rr; }
    else {
        int a = rr + j;       if (a >= 63) a -= 63;
        int c = rr + 63 - j;  if (c >= 63) c -= 63;
        p = a; q = c;
    }
}

union SMu {
    float ytT[128][68];   // syrk staging, transposed (34816 B)
    float G[64][68];      // one-sided Jacobi working matrix, col-major (17408 B)
};

__global__ __launch_bounds__(1024) void k_eig(
    const float* __restrict__ y, const float* __restrict__ hpart,
    const float* __restrict__ fcw, const float* __restrict__ fcb,
    float* __restrict__ out)
{
    const int b    = blockIdx.x;
    const int tid  = threadIdx.x;
    const int w    = tid >> 6;     // wave 0..15
    const int lane = tid & 63;
    const int grp  = lane >> 5;    // 0/1: two pair-groups per wave
    const int gl   = lane & 31;

    __shared__ SMu U;
    __shared__ float nrm[64];
    __shared__ float le[64];
    __shared__ float wred2[16];

    // ---- syrk: acc = y y^T; transposed staging, b128 MAC on 256 thr ----
    const int mg = tid >> 4, ng = tid & 15;       // valid for tid<256
    const int m0 = mg * 4,  n0 = ng * 4;
    float acc[16];
    #pragma unroll
    for (int i = 0; i < 16; ++i) acc[i] = 0.f;
    for (int tile = 0; tile < 8; ++tile) {
        #pragma unroll
        for (int k = 0; k < 8; ++k) {
            int idx = tid + k*1024;
            int col = idx >> 7, row = idx & 127;   // col=m, row=t-in-tile
            int tg = tile * 128 + row;
            U.ytT[row][col] = (tg <= 1000) ? y[(b*64 + col)*1001 + tg] : 0.f;
        }
        __syncthreads();
        if (tid < 256) {
            for (int tt = 0; tt < 128; ++tt) {
                v4f ym = *(const v4f*)&U.ytT[tt][m0];
                v4f yn = *(const v4f*)&U.ytT[tt][n0];
                #pragma unroll
                for (int i = 0; i < 4; ++i)
                    #pragma unroll
                    for (int j = 0; j < 4; ++j) acc[i*4 + j] += ym[i] * yn[j];
            }
        }
        __syncthreads();
    }
    if (tid < 256) {
        float hs = hpart[b*4] + hpart[b*4+1] + hpart[b*4+2] + hpart[b*4+3];
        float mu = hs / (999.f * 450.f);
        #pragma unroll
        for (int i = 0; i < 4; ++i)
            #pragma unroll
            for (int j = 0; j < 4; ++j) {
                int mm = m0 + i, nn = n0 + j;
                U.G[mm][nn] = acc[i*4 + j] * (0.95f / 999.f)
                            + ((mm == nn) ? 0.05f * mu : 0.f);
            }
    }
    __syncthreads();

    // ---- initial column norms: nrm[k] = ||G col k||^2 ----
    {
        int gid = (w << 1) | grp;   // 0..31
        #pragma unroll
        for (int h = 0; h < 2; ++h) {
            int k = gid + 32*h;
            float2 gk = *(const float2*)&U.G[k][2*gl];
            float v = gk.x*gk.x + gk.y*gk.y;
            #pragma unroll
            for (int m = 1; m < 32; m <<= 1) v += __shfl_xor(v, m, 64);
            if (gl == 0) nrm[k] = v;
        }
    }
    __syncthreads();

    // ---- one-sided cyclic Jacobi: 32 pairs/round, 1 barrier/round ----
    // Group (w,grp) owns pair jj = w + 16*grp; lane gl holds rows 2gl,2gl+1
    // of both columns (b64).  gamma = gp.gq via 5-level butterfly; alpha,
    // beta tracked incrementally (a' = a - t*gam, b' = b + t*gam).
    const int jj = w + (grp << 4);
    for (int sweep = 0; sweep < MAXSWEEP; ++sweep) {
        int allc = 1;
        for (int rr = 0; rr < 63; ++rr) {
            int p, q; pair_pq(rr, jj, p, q);
            float2 gp = *(const float2*)&U.G[p][2*gl];
            float2 gq = *(const float2*)&U.G[q][2*gl];
            float gam = gp.x*gq.x + gp.y*gq.y;
            #pragma unroll
            for (int m = 1; m < 32; m <<= 1) gam += __shfl_xor(gam, m, 64);
            float al = nrm[p], be = nrm[q];
            if (fabsf(gam) > JTOL * sqrtf(al * be)) {
                allc = 0;
                float tau = (be - al) * __builtin_amdgcn_rcpf(2.f * gam);
                float t  = copysignf(1.f, tau) / (fabsf(tau) + sqrtf(1.f + tau*tau));
                float c  = rsqrtf(1.f + t*t);
                float s  = t * c;
                float2 np, nq;
                np.x = c*gp.x - s*gq.x;  np.y = c*gp.y - s*gq.y;
                nq.x = s*gp.x + c*gq.x;  nq.y = s*gp.y + c*gq.y;
                *(float2*)&U.G[p][2*gl] = np;
                *(float2*)&U.G[q][2*gl] = nq;
                if (gl == 0) { nrm[p] = al - t*gam; nrm[q] = be + t*gam; }
            }
            __syncthreads();
        }
        if (__syncthreads_and(allc)) break;
    }

    // ---- fresh column norms -> le[k] = log(lambda_k)/lambda_k^2 ----
    {
        int gid = (w << 1) | grp;
        #pragma unroll
        for (int h = 0; h < 2; ++h) {
            int k = gid + 32*h;
            float2 gk = *(const float2*)&U.G[k][2*gl];
            float v = gk.x*gk.x + gk.y*gk.y;
            #pragma unroll
            for (int m = 1; m < 32; m <<= 1) v += __shfl_xor(v, m, 64);
            if (gl == 0) {
                float n2 = fmaxf(v, 1e-12f);
                le[k] = 0.5f * logf(n2) / n2;   // log(sqrt(n2)) / n2
            }
        }
    }
    __syncthreads();

    // ---- log-eig reconstruction + FC (first 256 threads) ----
    // log_mapped = sum_k le[k] * g_k g_k^T   (g_k = col k of G, contiguous)
    if (tid < 256) {
        float lm[16];
        #pragma unroll
        for (int i = 0; i < 16; ++i) lm[i] = 0.f;
        for (int k = 0; k < 64; ++k) {
            float l = le[k];
            v4f gm = *(const v4f*)&U.G[k][m0];
            v4f gn = *(const v4f*)&U.G[k][n0];
            #pragma unroll
            for (int i = 0; i < 4; ++i) {
                float vm = gm[i] * l;
                #pragma unroll
                for (int j = 0; j < 4; ++j) lm[i*4 + j] += vm * gn[j];
            }
        }

        float fa[4];
        #pragma unroll
        for (int o = 0; o < 4; ++o) fa[o] = 0.f;
        #pragma unroll
        for (int i = 0; i < 4; ++i)
            #pragma unroll
            for (int j = 0; j < 4; ++j) {
                int gi = m0 + i, gj = n0 + j;
                if (gi <= gj) {
                    int p = gi*64 - (gi*(gi-1))/2 + (gj - gi);
                    float lv = lm[i*4 + j];
                    #pragma unroll
                    for (int o = 0; o < 4; ++o) fa[o] += lv * fcw[o*2080 + p];
                }
            }

        #pragma unroll
        for (int o = 0; o < 4; ++o)
            for (int off = 32; off > 0; off >>= 1)
                fa[o] += __shfl_down(fa[o], off, 64);
        if (lane == 0) {
            #pragma unroll
            for (int o = 0; o < 4; ++o) wred2[w*4 + o] = fa[o];
        }
    }
    __syncthreads();
    if (tid < 4)
        out[b*4 + tid] = wred2[tid] + wred2[4 + tid] + wred2[8 + tid]
                       + wred2[12 + tid] + fcb[tid];
}

// ---------------------------------------------------------------------------
extern "C" void kernel_launch(void* const* d_in, const int* in_sizes, int n_in,
                              void* d_out, int out_size, void* d_ws, size_t ws_size,
                              hipStream_t stream) {
    (void)in_sizes; (void)n_in; (void)out_size; (void)ws_size;
    const float* x   = (const float*)d_in[0];
    const float* ws0 = (const float*)d_in[1];
    const float* ws1 = (const float*)d_in[2];
    const float* ws2 = (const float*)d_in[3];
    const float* bsg = (const float*)d_in[4];
    const float* bsb = (const float*)d_in[5];
    const float* bsm = (const float*)d_in[6];
    const float* bsv = (const float*)d_in[7];
    const float* wf  = (const float*)d_in[8];
    const float* bfg = (const float*)d_in[9];
    const float* bfb = (const float*)d_in[10];
    const float* bfm = (const float*)d_in[11];
    const float* bfv = (const float*)d_in[12];
    const float* wt0 = (const float*)d_in[13];
    const float* wt1 = (const float*)d_in[14];
    const float* wt2 = (const float*)d_in[15];
    const float* btg = (const float*)d_in[16];
    const float* btb = (const float*)d_in[17];
    const float* btm = (const float*)d_in[18];
    const float* btv = (const float*)d_in[19];
    const float* Wm  = (const float*)d_in[20];
    const float* fcw = (const float*)d_in[21];
    const float* fcb = (const float*)d_in[22];

    float* wsf   = (float*)d_ws;
    float* yb    = wsf + WS_Y;
    float* hpart = wsf + WS_HPART;

    k_prep<<<1, 512, 0, stream>>>(ws0, ws1, ws2, bsg, bsb, bsm, bsv,
                                  wf, bfg, bfb, bfm, bfv,
                                  wt0, wt1, wt2, btg, btb, btm, btv, wsf);
    k_main<<<512, 256, 0, stream>>>(x, wsf, Wm, yb, hpart);
    k_eig<<<128, 1024, 0, stream>>>(yb, hpart, fcw, fcb, (float*)d_out);
}